// Round 1
// baseline (390.197 us; speedup 1.0000x reference)
//
#include <hip/hip_runtime.h>

constexpr int NB = 256;   // batch
constexpr int NS = 64;    // seq len
constexpr int NN = 64;    // tree nodes
constexpr int NE = 300;   // embedding dim
constexpr int NH = 600;   // hidden dim

typedef __attribute__((ext_vector_type(8))) short bf16x8;
typedef __attribute__((ext_vector_type(4))) float f32x4;

// ---------------- workspace layout (float-indexed) ----------------
constexpr size_t OFF_REP = 0;                           // [2][NB][NE]
constexpr size_t SZ_REP  = (size_t)2*NB*NE;
constexpr size_t OFF_ROOT= OFF_REP + SZ_REP;            // [2][NB][NE]
constexpr size_t OFF_WBF = OFF_ROOT + SZ_REP;           // W_enc bf16 B-frag swizzled
constexpr size_t SZ_WBF  = (size_t)3*20*10*64*8/2;      // 153,600 floats
constexpr size_t OFF_W0T = OFF_WBF + SZ_WBF;            // W0^T [1800][600]
constexpr size_t SZ_W0T  = (size_t)6*NE*NH;
constexpr size_t OFF_W1T = OFF_W0T + SZ_W0T;            // W1^T [600][600]
constexpr size_t SZ_WH   = (size_t)NH*NH;
constexpr size_t OFF_W2T = OFF_W1T + SZ_WH;             // W2^T [600][600]
constexpr size_t OFF_H1  = OFF_W2T + SZ_WH;             // [NB][NH]
constexpr size_t SZ_HB   = (size_t)NB*NH;
constexpr size_t OFF_H2  = OFF_H1 + SZ_HB;
constexpr size_t OFF_H3  = OFF_H2 + SZ_HB;

__device__ __forceinline__ ushort f2bf(float x) {
  unsigned u = __float_as_uint(x);
  unsigned r = (u + 0x7FFFu + ((u >> 16) & 1u)) >> 16;   // RNE
  return (ushort)r;
}
__device__ __forceinline__ float bf2f(ushort u) {
  return __uint_as_float(((unsigned)u) << 16);
}

// ---------------- k_setup: bias-init + Wbf swizzle + MLP weight transposes ---
constexpr int BIAS4 = NB*NH/4;            // 38400 float4 per layer
constexpr int NSWZ  = 3*20*10*64;         // 38400 lane-frags
constexpr int PREP_ITEMS  = 3*BIAS4 + NSWZ;                      // 153600
constexpr int PREP_BLOCKS = (PREP_ITEMS + 255)/256;              // 600
constexpr int TR_BLOCKS   = 57*19*3;                             // 3249
constexpr int SETUP_BLOCKS = PREP_BLOCKS + TR_BLOCKS;

__global__ __launch_bounds__(256)
void k_setup(const float* __restrict__ Wenc, const float* __restrict__ b0,
             const float* __restrict__ b1, const float* __restrict__ b2,
             const float* __restrict__ W0, const float* __restrict__ W1,
             const float* __restrict__ W2,
             float* __restrict__ h1, float* __restrict__ h2, float* __restrict__ h3,
             ushort* __restrict__ Wbf,
             float* __restrict__ W0T, float* __restrict__ W1T, float* __restrict__ W2T) {
  __shared__ float tile[32][33];
  if (blockIdx.x < PREP_BLOCKS) {
    int t = blockIdx.x*256 + threadIdx.x;
    if (t < 3*BIAS4) {
      int layer = t / BIAS4, i = t % BIAS4;
      const float* bs = layer==0 ? b0 : (layer==1 ? b1 : b2);
      float* hd = layer==0 ? h1 : (layer==1 ? h2 : h3);
      reinterpret_cast<float4*>(hd)[i] = reinterpret_cast<const float4*>(bs)[i % 150];
      return;
    }
    t -= 3*BIAS4;
    if (t < NSWZ) {
      // Wbf[(((r*20+nt)*10+ks)*64+lane)*8+j] = bf16(Wenc[r][f][e]),
      // f = nt*16+(lane&15), e = ks*32+(lane>>4)*8+j, zero-padded past 300.
      int lane = t & 63, rest = t >> 6;
      int ksi = rest % 10, rnt = rest / 10, nt = rnt % 20, r = rnt / 20;
      int f = nt*16 + (lane & 15), e0 = ksi*32 + (lane >> 4)*8;
      ushort v[8];
      #pragma unroll
      for (int j = 0; j < 8; j++) {
        int e = e0 + j;
        v[j] = (f < NE && e < NE) ? f2bf(Wenc[((size_t)r*NE + f)*NE + e]) : (ushort)0;
      }
      *reinterpret_cast<int4*>(&Wbf[(size_t)t*8]) = *reinterpret_cast<const int4*>(v);
    }
    return;
  }
  // transpose tiles (coalesced both sides)
  int idx = blockIdx.x - PREP_BLOCKS;
  int z = idx / (57*19), rem = idx % (57*19);
  int by = rem / 57, bx = rem % 57;
  const float* W = z==0 ? W0 : (z==1 ? W1 : W2);
  float* WT = z==0 ? W0T : (z==1 ? W1T : W2T);
  int K = z==0 ? 1800 : 600;               // W [600][K] -> WT [K][600]
  int k0 = bx * 32, j0 = by * 32;
  if (k0 >= K) return;
  int tx = threadIdx.x & 31, ty = threadIdx.x >> 5;
  for (int yy = ty; yy < 32; yy += 8) {
    int j = j0 + yy, k = k0 + tx;
    if (j < 600 && k < K) tile[yy][tx] = W[(size_t)j*K + k];
  }
  __syncthreads();
  for (int yy = ty; yy < 32; yy += 8) {
    int k = k0 + yy, j = j0 + tx;
    if (k < K && j < 600) WT[(size_t)k*600 + j] = tile[tx][yy];
  }
}

// ---------------- k_tree: whole tree for one (s,b) per block ----------------
// hS bf16 [64][328] (MFMA-A layout). 3 phases: L3 (children 21..63, 3 M-tiles,
// af[3][10] in regs so each B-frag feeds 3 MFMAs), L2 (5..20), L1 (1..4).
// Transform t written IN PLACE (bf16) over the child's hS row; parent update
// then reads hS uniformly (t if rel in 0..2, else word).
constexpr int TS = 328;   // row stride (ushorts): 656B -> 2-way bank alias (free)

__global__ __launch_bounds__(256)
void k_tree(const int* __restrict__ px, const int* __restrict__ hx,
            const int* __restrict__ pwi, const int* __restrict__ prel,
            const int* __restrict__ hwi, const int* __restrict__ hrel,
            const float* __restrict__ Etab, const ushort* __restrict__ Wbf,
            float* __restrict__ rep, float* __restrict__ root) {
  __shared__ __align__(16) ushort hS[64*TS];   // 41,984 B
  __shared__ int xsh[64];
  __shared__ int wish[64];
  __shared__ int relsh[64];
  const int sb = blockIdx.x;
  const int s = sb >> 8, b = sb & 255;
  const int tid = threadIdx.x;

  if (tid < 64) xsh[tid] = ((s ? hx : px) + b*NS)[tid];
  else if (tid < 128) wish[tid-64] = ((s ? hwi : pwi) + b*NN)[tid-64];
  else if (tid < 192) relsh[tid-128] = ((s ? hrel : prel) + b*NN)[tid-128];
  __syncthreads();

  // rep = sum of 64 seq-embedding rows (coalesced, unroll-8 for ILP)
  for (int e = tid; e < NE; e += 256) {
    float acc = 0.f;
    #pragma unroll 8
    for (int j = 0; j < NS; j++) acc += Etab[(size_t)xsh[j]*NE + e];
    rep[(size_t)sb*NE + e] = acc;
  }
  // word build: flat float4 loop, 4800 independent chunks (good MLP)
  for (int flat = tid; flat < 64*75; flat += 256) {
    int n = flat / 75, c = flat % 75;
    int w = wish[n];
    float4 v;
    if (w < 0) v = float4{1.f,1.f,1.f,1.f};
    else v = *reinterpret_cast<const float4*>(&Etab[(size_t)xsh[w]*NE + c*4]);
    ushort4 o; o.x = f2bf(v.x); o.y = f2bf(v.y); o.z = f2bf(v.z); o.w = f2bf(v.w);
    *reinterpret_cast<ushort4*>(&hS[n*TS + c*4]) = o;
  }
  // zero-pad K region e in [300,320)
  for (int z = tid; z < 64*10; z += 256) {
    int row = z / 10, cc = z % 10;
    *reinterpret_cast<unsigned*>(&hS[row*TS + 300 + cc*2]) = 0u;
  }
  __syncthreads();

  const int wave = tid >> 6, lane = tid & 63;
  const int mrow = lane & 15, quad = lane >> 4;

  // ===== Phase L3: children 21..63 (M-tiles at 21/37/53), parents 5..15 =====
  {
    const int mb0 = 21, mb1 = 37, mb2 = 53;
    bf16x8 af[3][10];
    #pragma unroll
    for (int ks = 0; ks < 10; ks++) {
      af[0][ks] = *reinterpret_cast<const bf16x8*>(&hS[(mb0+mrow)*TS + ks*32 + quad*8]);
      af[1][ks] = *reinterpret_cast<const bf16x8*>(&hS[(mb1+mrow)*TS + ks*32 + quad*8]);
      int r2 = min(mb2+mrow, 63);
      af[2][ks] = *reinterpret_cast<const bf16x8*>(&hS[r2*TS + ks*32 + quad*8]);
    }
    __syncthreads();   // all af registered before in-place overwrite
    for (int pr = wave; pr < 57; pr += 4) {
      int r = pr / 19, nt = pr % 19;
      const ushort* Wb = &Wbf[(size_t)((r*20 + nt)*10)*64*8];
      f32x4 acc0 = f32x4{0.f,0.f,0.f,0.f};
      f32x4 acc1 = f32x4{0.f,0.f,0.f,0.f};
      f32x4 acc2 = f32x4{0.f,0.f,0.f,0.f};
      #pragma unroll
      for (int ks = 0; ks < 10; ks++) {
        bf16x8 bf = *reinterpret_cast<const bf16x8*>(&Wb[((size_t)ks*64 + lane)*8]);
        acc0 = __builtin_amdgcn_mfma_f32_16x16x32_bf16(af[0][ks], bf, acc0, 0, 0, 0);
        acc1 = __builtin_amdgcn_mfma_f32_16x16x32_bf16(af[1][ks], bf, acc1, 0, 0, 0);
        acc2 = __builtin_amdgcn_mfma_f32_16x16x32_bf16(af[2][ks], bf, acc2, 0, 0, 0);
      }
      int f = nt*16 + mrow;
      if (f < NE) {
        #pragma unroll
        for (int reg = 0; reg < 4; reg++) {
          int m = quad*4 + reg;
          int c0 = mb0 + m, c1 = mb1 + m, c2 = mb2 + m;
          if (relsh[c0] == r) hS[c0*TS + f] = f2bf(acc0[reg]);
          if (relsh[c1] == r) hS[c1*TS + f] = f2bf(acc1[reg]);
          if (c2 < 64 && relsh[c2] == r) hS[c2*TS + f] = f2bf(acc2[reg]);
        }
      }
    }
    __syncthreads();
    // parent update 5..15 (rows disjoint from children 21..63)
    for (int f = tid; f < NE; f += 256) {
      #pragma unroll
      for (int p = 5; p <= 15; p++) {
        int nc = (p == 15) ? 3 : 4;
        float sum = 0.f;
        for (int j = 0; j < nc; j++) sum += bf2f(hS[(4*p+1+j)*TS + f]);
        float v = bf2f(hS[p*TS + f]) * sum * (1.0f/(float)nc);
        hS[p*TS + f] = f2bf(v > 0.f ? v : 0.f);
      }
    }
    __syncthreads();
  }

  // ===== Phase L2: children 5..20 (one M-tile), parents 1..4 =====
  {
    bf16x8 af[10];
    #pragma unroll
    for (int ks = 0; ks < 10; ks++)
      af[ks] = *reinterpret_cast<const bf16x8*>(&hS[(5+mrow)*TS + ks*32 + quad*8]);
    __syncthreads();
    for (int pr = wave; pr < 57; pr += 4) {
      int r = pr / 19, nt = pr % 19;
      const ushort* Wb = &Wbf[(size_t)((r*20 + nt)*10)*64*8];
      f32x4 acc = f32x4{0.f,0.f,0.f,0.f};
      #pragma unroll
      for (int ks = 0; ks < 10; ks++) {
        bf16x8 bf = *reinterpret_cast<const bf16x8*>(&Wb[((size_t)ks*64 + lane)*8]);
        acc = __builtin_amdgcn_mfma_f32_16x16x32_bf16(af[ks], bf, acc, 0, 0, 0);
      }
      int f = nt*16 + mrow;
      if (f < NE) {
        #pragma unroll
        for (int reg = 0; reg < 4; reg++) {
          int c = 5 + quad*4 + reg;
          if (relsh[c] == r) hS[c*TS + f] = f2bf(acc[reg]);
        }
      }
    }
    __syncthreads();
    for (int f = tid; f < NE; f += 256) {
      #pragma unroll
      for (int p = 1; p <= 4; p++) {
        float sum = 0.f;
        #pragma unroll
        for (int j = 0; j < 4; j++) sum += bf2f(hS[(4*p+1+j)*TS + f]);
        float v = bf2f(hS[p*TS + f]) * sum * 0.25f;
        hS[p*TS + f] = f2bf(v > 0.f ? v : 0.f);
      }
    }
    __syncthreads();
  }

  // ===== Phase L1: children 1..4, parent 0 (root) =====
  {
    bool rp0 = (relsh[1]==0)|(relsh[2]==0)|(relsh[3]==0)|(relsh[4]==0);
    bool rp1 = (relsh[1]==1)|(relsh[2]==1)|(relsh[3]==1)|(relsh[4]==1);
    bool rp2 = (relsh[1]==2)|(relsh[2]==2)|(relsh[3]==2)|(relsh[4]==2);
    bf16x8 af[10];
    #pragma unroll
    for (int ks = 0; ks < 10; ks++)
      af[ks] = *reinterpret_cast<const bf16x8*>(&hS[(1+min(mrow,3))*TS + ks*32 + quad*8]);
    __syncthreads();
    for (int pr = wave; pr < 57; pr += 4) {
      int r = pr / 19, nt = pr % 19;
      if ((r==0 && !rp0) || (r==1 && !rp1) || (r==2 && !rp2)) continue;
      const ushort* Wb = &Wbf[(size_t)((r*20 + nt)*10)*64*8];
      f32x4 acc = f32x4{0.f,0.f,0.f,0.f};
      #pragma unroll
      for (int ks = 0; ks < 10; ks++) {
        bf16x8 bf = *reinterpret_cast<const bf16x8*>(&Wb[((size_t)ks*64 + lane)*8]);
        acc = __builtin_amdgcn_mfma_f32_16x16x32_bf16(af[ks], bf, acc, 0, 0, 0);
      }
      int f = nt*16 + mrow;
      if (f < NE) {
        #pragma unroll
        for (int reg = 0; reg < 4; reg++) {
          int m = quad*4 + reg;
          if (m < 4 && relsh[1+m] == r) hS[(1+m)*TS + f] = f2bf(acc[reg]);
        }
      }
    }
    __syncthreads();
    for (int f = tid; f < NE; f += 256) {
      float sum = 0.f;
      #pragma unroll
      for (int c = 1; c <= 4; c++) sum += bf2f(hS[c*TS + f]);
      float v = bf2f(hS[0*TS + f]) * sum * 0.25f;
      root[(size_t)sb*NE + f] = v > 0.f ? v : 0.f;
    }
  }
}

// ---------------- k_fc: split-K FC partial ----------------
// block = 64b x 64j tile, thread = 4b x 4j, K-chunk per blockIdx.z.
// Partials atomicAdd onto bias-initialized out.
// mode 0/1: (relu) input; mode 2: build concat feature on the fly:
// x = [p_rep, h_rep, p-h, p*h, psg-hsg, psg*hsg] from rep/root.
__global__ __launch_bounds__(256)
void k_fc(const float* __restrict__ in, const float* __restrict__ WTm,
          float* __restrict__ out, int K, int kc, int mode,
          const float* __restrict__ rep, const float* __restrict__ root) {
  __shared__ __align__(16) float xl[150*68];
  int b0 = blockIdx.x * 64;
  int j0 = blockIdx.y * 64;
  int k0 = blockIdx.z * kc;
  int tid = threadIdx.x;
  if (mode == 2) {
    for (int flat = tid; flat < kc*64; flat += 256) {
      int bbp = flat / kc, k = flat % kc;
      int kg = k0 + k, seg = kg / NE, e = kg % NE;
      int b = b0 + bbp;
      float v;
      switch (seg) {
        case 0: v = rep[(size_t)b*NE + e]; break;
        case 1: v = rep[(size_t)(NB+b)*NE + e]; break;
        case 2: v = rep[(size_t)b*NE + e] - rep[(size_t)(NB+b)*NE + e]; break;
        case 3: v = rep[(size_t)b*NE + e] * rep[(size_t)(NB+b)*NE + e]; break;
        case 4: v = root[(size_t)b*NE + e] - root[(size_t)(NB+b)*NE + e]; break;
        default: v = root[(size_t)b*NE + e] * root[(size_t)(NB+b)*NE + e]; break;
      }
      xl[k*68 + bbp] = v;
    }
  } else {
    for (int flat = tid; flat < kc*64; flat += 256) {
      int bbp = flat / kc, k = flat % kc;
      float v = in[(size_t)(b0+bbp)*K + k0 + k];
      if (mode == 1) v = fmaxf(v, 0.f);
      xl[k*68 + bbp] = v;
    }
  }
  __syncthreads();
  int tj = tid & 15, tb = tid >> 4;
  int j = j0 + tj*4;
  if (j + 3 >= NH) return;
  float acc[4][4];
  #pragma unroll
  for (int a = 0; a < 4; a++)
    #pragma unroll
    for (int bq = 0; bq < 4; bq++) acc[a][bq] = 0.f;
  for (int k = 0; k < kc; k++) {
    const float4 w  = *reinterpret_cast<const float4*>(&WTm[(size_t)(k0+k)*NH + j]);
    const float4 xv = *reinterpret_cast<const float4*>(&xl[k*68 + tb*4]);
    acc[0][0] += xv.x*w.x; acc[0][1] += xv.x*w.y; acc[0][2] += xv.x*w.z; acc[0][3] += xv.x*w.w;
    acc[1][0] += xv.y*w.x; acc[1][1] += xv.y*w.y; acc[1][2] += xv.y*w.z; acc[1][3] += xv.y*w.w;
    acc[2][0] += xv.z*w.x; acc[2][1] += xv.z*w.y; acc[2][2] += xv.z*w.z; acc[2][3] += xv.z*w.w;
    acc[3][0] += xv.w*w.x; acc[3][1] += xv.w*w.y; acc[3][2] += xv.w*w.z; acc[3][3] += xv.w*w.w;
  }
  #pragma unroll
  for (int bi = 0; bi < 4; bi++)
    #pragma unroll
    for (int ji = 0; ji < 4; ji++)
      atomicAdd(&out[(size_t)(b0 + tb*4 + bi)*NH + j + ji], acc[bi][ji]);
}

// Final 600->3 layer; one wave per batch row; relu(h3) folded into load.
__global__ __launch_bounds__(64)
void k_out(const float* __restrict__ h3, const float* __restrict__ Wout,
           const float* __restrict__ bout, float* __restrict__ out) {
  int b = blockIdx.x, tid = threadIdx.x;
  float a0 = 0.f, a1 = 0.f, a2 = 0.f;
  for (int k = tid; k < NH; k += 64) {
    float xv = fmaxf(h3[(size_t)b*NH + k], 0.f);
    a0 += xv * Wout[k];
    a1 += xv * Wout[NH + k];
    a2 += xv * Wout[2*NH + k];
  }
  #pragma unroll
  for (int off = 32; off > 0; off >>= 1) {
    a0 += __shfl_down(a0, off, 64);
    a1 += __shfl_down(a1, off, 64);
    a2 += __shfl_down(a2, off, 64);
  }
  if (tid == 0) {
    out[b*3 + 0] = a0 + bout[0];
    out[b*3 + 1] = a1 + bout[1];
    out[b*3 + 2] = a2 + bout[2];
  }
}

// ---------------- launch ----------------
extern "C" void kernel_launch(void* const* d_in, const int* in_sizes, int n_in,
                              void* d_out, int out_size, void* d_ws, size_t ws_size,
                              hipStream_t stream) {
  const int*   px    = (const int*)d_in[0];
  const int*   hx    = (const int*)d_in[1];
  const int*   pwi   = (const int*)d_in[2];
  const int*   prel  = (const int*)d_in[3];
  const int*   hwi   = (const int*)d_in[4];
  const int*   hrel  = (const int*)d_in[5];
  // d_in[6]=parent, d_in[7]=level: fixed 4-ary tree, hardcoded
  const float* Etab  = (const float*)d_in[8];
  const float* Wenc  = (const float*)d_in[9];
  const float* W0w   = (const float*)d_in[10];
  const float* W0b   = (const float*)d_in[11];
  const float* W1w   = (const float*)d_in[12];
  const float* W1b   = (const float*)d_in[13];
  const float* W2w   = (const float*)d_in[14];
  const float* W2b   = (const float*)d_in[15];
  const float* Woutw = (const float*)d_in[16];
  const float* Woutb = (const float*)d_in[17];

  float* ws   = (float*)d_ws;
  float* rep  = ws + OFF_REP;
  float* root = ws + OFF_ROOT;
  ushort* Wbf = (ushort*)(ws + OFF_WBF);
  float* W0T  = ws + OFF_W0T;
  float* W1T  = ws + OFF_W1T;
  float* W2T  = ws + OFF_W2T;
  float* h1   = ws + OFF_H1;
  float* h2   = ws + OFF_H2;
  float* h3   = ws + OFF_H3;
  float* outp = (float*)d_out;

  dim3 blk(256);
  k_setup<<<dim3(SETUP_BLOCKS), blk, 0, stream>>>(
      Wenc, W0b, W1b, W2b, W0w, W1w, W2w, h1, h2, h3, Wbf, W0T, W1T, W2T);
  k_tree<<<dim3(2*NB), blk, 0, stream>>>(
      px, hx, pwi, prel, hwi, hrel, Etab, Wbf, rep, root);
  k_fc<<<dim3(4, 10, 12), blk, 0, stream>>>(nullptr, W0T, h1, 6*NE, 150, 2, rep, root);
  k_fc<<<dim3(4, 10, 8), blk, 0, stream>>>(h1, W1T, h2, NH, 75, 1, nullptr, nullptr);
  k_fc<<<dim3(4, 10, 8), blk, 0, stream>>>(h2, W2T, h3, NH, 75, 1, nullptr, nullptr);
  k_out<<<dim3(NB), dim3(64), 0, stream>>>(h3, Woutw, Woutb, outp);
}

// Round 2
// 314.166 us; speedup vs baseline: 1.2420x; 1.2420x over previous
//
#include <hip/hip_runtime.h>

constexpr int NB = 256;   // batch
constexpr int NS = 64;    // seq len
constexpr int NN = 64;    // tree nodes
constexpr int NE = 300;   // embedding dim
constexpr int NH = 600;   // hidden dim

typedef __attribute__((ext_vector_type(8))) short bf16x8;
typedef __attribute__((ext_vector_type(4))) float f32x4;

// FC GEMM geometry: K padded to 32, N padded to 640 (40 j-tiles of 16)
constexpr int KT0 = 57;   // ceil(1800/32)  -> K=1824 for layer 0
constexpr int KT1 = 19;   // ceil(600/32)   -> K=608 for layers 1/2
constexpr int NJT = 40;   // 640 / 16 j-tiles
constexpr int HP  = 640;  // h row stride in ushorts (cols 600..607 zeroed, 608.. unused)

// ---------------- workspace layout (float-indexed) ----------------
constexpr size_t OFF_REP = 0;                           // [2][NB][NE] fp32
constexpr size_t SZ_REP  = (size_t)2*NB*NE;
constexpr size_t OFF_ROOT= OFF_REP + SZ_REP;            // [2][NB][NE] fp32
constexpr size_t OFF_WBF = OFF_ROOT + SZ_REP;           // tree W_enc bf16 B-frag swizzled
constexpr size_t SZ_WBF  = (size_t)3*20*10*64*8/2;      // 153,600 floats
constexpr size_t OFF_W0S = OFF_WBF + SZ_WBF;            // W0 bf16 B-frag swizzled
constexpr size_t SZ_W0S  = (size_t)KT0*NJT*64*8/2;      // 583,680 floats
constexpr size_t OFF_W1S = OFF_W0S + SZ_W0S;
constexpr size_t SZ_W1S  = (size_t)KT1*NJT*64*8/2;      // 194,560 floats
constexpr size_t OFF_W2S = OFF_W1S + SZ_W1S;
constexpr size_t OFF_XSW = OFF_W2S + SZ_W1S;            // X bf16 A-frag swizzled
constexpr size_t SZ_XSW  = (size_t)KT0*16*64*8/2;       // 233,472 floats
constexpr size_t OFF_H1  = OFF_XSW + SZ_XSW;            // h bf16 [NB][HP]
constexpr size_t SZ_H    = (size_t)NB*HP/2;             // 81,920 floats
constexpr size_t OFF_H2  = OFF_H1 + SZ_H;
constexpr size_t OFF_H3  = OFF_H2 + SZ_H;

__device__ __forceinline__ ushort f2bf(float x) {
  unsigned u = __float_as_uint(x);
  unsigned r = (u + 0x7FFFu + ((u >> 16) & 1u)) >> 16;   // RNE
  return (ushort)r;
}
__device__ __forceinline__ float bf2f(ushort u) {
  return __uint_as_float(((unsigned)u) << 16);
}

// ---------------- k_setup: tree-W swizzle + FC weight bf16 B-frag swizzles ---
// B-frag layout (mfma_f32_16x16x32_bf16): lane holds col n=lane&15,
// k = (lane>>4)*8 + i. Stored as [(kt*NJT + jt)*64 + lane][8].
constexpr int NSWZ = 3*20*10*64;          // 38400 tree lane-frags
constexpr int N0S  = KT0*NJT*64;          // 145,920
constexpr int N1S  = KT1*NJT*64;          // 48,640
constexpr int SETUP_ITEMS  = NSWZ + N0S + 2*N1S;   // 281,600
constexpr int SETUP_BLOCKS = SETUP_ITEMS/256;      // 1100 exactly

__global__ __launch_bounds__(256)
void k_setup(const float* __restrict__ Wenc, const float* __restrict__ W0,
             const float* __restrict__ W1, const float* __restrict__ W2,
             ushort* __restrict__ Wbf, ushort* __restrict__ W0S,
             ushort* __restrict__ W1S, ushort* __restrict__ W2S) {
  int t = blockIdx.x*256 + threadIdx.x;
  if (t < NSWZ) {
    // tree weights: Wbf[(((r*20+nt)*10+ks)*64+lane)*8+j] = bf16(Wenc[r][f][e])
    int lane = t & 63, rest = t >> 6;
    int ksi = rest % 10, rnt = rest / 10, nt = rnt % 20, r = rnt / 20;
    int f = nt*16 + (lane & 15), e0 = ksi*32 + (lane >> 4)*8;
    ushort v[8];
    #pragma unroll
    for (int j = 0; j < 8; j++) {
      int e = e0 + j;
      v[j] = (f < NE && e < NE) ? f2bf(Wenc[((size_t)r*NE + f)*NE + e]) : (ushort)0;
    }
    *reinterpret_cast<int4*>(&Wbf[(size_t)t*8]) = *reinterpret_cast<const int4*>(v);
    return;
  }
  t -= NSWZ;
  const float* W; ushort* D; int K;
  if (t < N0S)              { W = W0; D = W0S; K = 6*NE; }
  else { t -= N0S;
    if (t < N1S)            { W = W1; D = W1S; K = NH; }
    else { t -= N1S;          W = W2; D = W2S; K = NH; } }
  int lane = t & 63, g = t >> 6;
  int jt = g % NJT, kt = g / NJT;
  int j  = jt*16 + (lane & 15);
  int kb = kt*32 + (lane >> 4)*8;
  ushort v[8];
  #pragma unroll
  for (int i = 0; i < 8; i++) {
    int k = kb + i;
    v[i] = (j < NH && k < K) ? f2bf(W[(size_t)j*K + k]) : (ushort)0;
  }
  *reinterpret_cast<int4*>(&D[(size_t)t*8]) = *reinterpret_cast<const int4*>(v);
}

// ---------------- k_tree: whole tree for one (s,b) per block (UNCHANGED) ----
constexpr int TS = 328;   // row stride (ushorts): 656B -> 2-way bank alias (free)

__global__ __launch_bounds__(256)
void k_tree(const int* __restrict__ px, const int* __restrict__ hx,
            const int* __restrict__ pwi, const int* __restrict__ prel,
            const int* __restrict__ hwi, const int* __restrict__ hrel,
            const float* __restrict__ Etab, const ushort* __restrict__ Wbf,
            float* __restrict__ rep, float* __restrict__ root) {
  __shared__ __align__(16) ushort hS[64*TS];   // 41,984 B
  __shared__ int xsh[64];
  __shared__ int wish[64];
  __shared__ int relsh[64];
  const int sb = blockIdx.x;
  const int s = sb >> 8, b = sb & 255;
  const int tid = threadIdx.x;

  if (tid < 64) xsh[tid] = ((s ? hx : px) + b*NS)[tid];
  else if (tid < 128) wish[tid-64] = ((s ? hwi : pwi) + b*NN)[tid-64];
  else if (tid < 192) relsh[tid-128] = ((s ? hrel : prel) + b*NN)[tid-128];
  __syncthreads();

  for (int e = tid; e < NE; e += 256) {
    float acc = 0.f;
    #pragma unroll 8
    for (int j = 0; j < NS; j++) acc += Etab[(size_t)xsh[j]*NE + e];
    rep[(size_t)sb*NE + e] = acc;
  }
  for (int flat = tid; flat < 64*75; flat += 256) {
    int n = flat / 75, c = flat % 75;
    int w = wish[n];
    float4 v;
    if (w < 0) v = float4{1.f,1.f,1.f,1.f};
    else v = *reinterpret_cast<const float4*>(&Etab[(size_t)xsh[w]*NE + c*4]);
    ushort4 o; o.x = f2bf(v.x); o.y = f2bf(v.y); o.z = f2bf(v.z); o.w = f2bf(v.w);
    *reinterpret_cast<ushort4*>(&hS[n*TS + c*4]) = o;
  }
  for (int z = tid; z < 64*10; z += 256) {
    int row = z / 10, cc = z % 10;
    *reinterpret_cast<unsigned*>(&hS[row*TS + 300 + cc*2]) = 0u;
  }
  __syncthreads();

  const int wave = tid >> 6, lane = tid & 63;
  const int mrow = lane & 15, quad = lane >> 4;

  // ===== Phase L3 =====
  {
    const int mb0 = 21, mb1 = 37, mb2 = 53;
    bf16x8 af[3][10];
    #pragma unroll
    for (int ks = 0; ks < 10; ks++) {
      af[0][ks] = *reinterpret_cast<const bf16x8*>(&hS[(mb0+mrow)*TS + ks*32 + quad*8]);
      af[1][ks] = *reinterpret_cast<const bf16x8*>(&hS[(mb1+mrow)*TS + ks*32 + quad*8]);
      int r2 = min(mb2+mrow, 63);
      af[2][ks] = *reinterpret_cast<const bf16x8*>(&hS[r2*TS + ks*32 + quad*8]);
    }
    __syncthreads();
    for (int pr = wave; pr < 57; pr += 4) {
      int r = pr / 19, nt = pr % 19;
      const ushort* Wb = &Wbf[(size_t)((r*20 + nt)*10)*64*8];
      f32x4 acc0 = f32x4{0.f,0.f,0.f,0.f};
      f32x4 acc1 = f32x4{0.f,0.f,0.f,0.f};
      f32x4 acc2 = f32x4{0.f,0.f,0.f,0.f};
      #pragma unroll
      for (int ks = 0; ks < 10; ks++) {
        bf16x8 bf = *reinterpret_cast<const bf16x8*>(&Wb[((size_t)ks*64 + lane)*8]);
        acc0 = __builtin_amdgcn_mfma_f32_16x16x32_bf16(af[0][ks], bf, acc0, 0, 0, 0);
        acc1 = __builtin_amdgcn_mfma_f32_16x16x32_bf16(af[1][ks], bf, acc1, 0, 0, 0);
        acc2 = __builtin_amdgcn_mfma_f32_16x16x32_bf16(af[2][ks], bf, acc2, 0, 0, 0);
      }
      int f = nt*16 + mrow;
      if (f < NE) {
        #pragma unroll
        for (int reg = 0; reg < 4; reg++) {
          int m = quad*4 + reg;
          int c0 = mb0 + m, c1 = mb1 + m, c2 = mb2 + m;
          if (relsh[c0] == r) hS[c0*TS + f] = f2bf(acc0[reg]);
          if (relsh[c1] == r) hS[c1*TS + f] = f2bf(acc1[reg]);
          if (c2 < 64 && relsh[c2] == r) hS[c2*TS + f] = f2bf(acc2[reg]);
        }
      }
    }
    __syncthreads();
    for (int f = tid; f < NE; f += 256) {
      #pragma unroll
      for (int p = 5; p <= 15; p++) {
        int nc = (p == 15) ? 3 : 4;
        float sum = 0.f;
        for (int j = 0; j < nc; j++) sum += bf2f(hS[(4*p+1+j)*TS + f]);
        float v = bf2f(hS[p*TS + f]) * sum * (1.0f/(float)nc);
        hS[p*TS + f] = f2bf(v > 0.f ? v : 0.f);
      }
    }
    __syncthreads();
  }

  // ===== Phase L2 =====
  {
    bf16x8 af[10];
    #pragma unroll
    for (int ks = 0; ks < 10; ks++)
      af[ks] = *reinterpret_cast<const bf16x8*>(&hS[(5+mrow)*TS + ks*32 + quad*8]);
    __syncthreads();
    for (int pr = wave; pr < 57; pr += 4) {
      int r = pr / 19, nt = pr % 19;
      const ushort* Wb = &Wbf[(size_t)((r*20 + nt)*10)*64*8];
      f32x4 acc = f32x4{0.f,0.f,0.f,0.f};
      #pragma unroll
      for (int ks = 0; ks < 10; ks++) {
        bf16x8 bf = *reinterpret_cast<const bf16x8*>(&Wb[((size_t)ks*64 + lane)*8]);
        acc = __builtin_amdgcn_mfma_f32_16x16x32_bf16(af[ks], bf, acc, 0, 0, 0);
      }
      int f = nt*16 + mrow;
      if (f < NE) {
        #pragma unroll
        for (int reg = 0; reg < 4; reg++) {
          int c = 5 + quad*4 + reg;
          if (relsh[c] == r) hS[c*TS + f] = f2bf(acc[reg]);
        }
      }
    }
    __syncthreads();
    for (int f = tid; f < NE; f += 256) {
      #pragma unroll
      for (int p = 1; p <= 4; p++) {
        float sum = 0.f;
        #pragma unroll
        for (int j = 0; j < 4; j++) sum += bf2f(hS[(4*p+1+j)*TS + f]);
        float v = bf2f(hS[p*TS + f]) * sum * 0.25f;
        hS[p*TS + f] = f2bf(v > 0.f ? v : 0.f);
      }
    }
    __syncthreads();
  }

  // ===== Phase L1 =====
  {
    bool rp0 = (relsh[1]==0)|(relsh[2]==0)|(relsh[3]==0)|(relsh[4]==0);
    bool rp1 = (relsh[1]==1)|(relsh[2]==1)|(relsh[3]==1)|(relsh[4]==1);
    bool rp2 = (relsh[1]==2)|(relsh[2]==2)|(relsh[3]==2)|(relsh[4]==2);
    bf16x8 af[10];
    #pragma unroll
    for (int ks = 0; ks < 10; ks++)
      af[ks] = *reinterpret_cast<const bf16x8*>(&hS[(1+min(mrow,3))*TS + ks*32 + quad*8]);
    __syncthreads();
    for (int pr = wave; pr < 57; pr += 4) {
      int r = pr / 19, nt = pr % 19;
      if ((r==0 && !rp0) || (r==1 && !rp1) || (r==2 && !rp2)) continue;
      const ushort* Wb = &Wbf[(size_t)((r*20 + nt)*10)*64*8];
      f32x4 acc = f32x4{0.f,0.f,0.f,0.f};
      #pragma unroll
      for (int ks = 0; ks < 10; ks++) {
        bf16x8 bf = *reinterpret_cast<const bf16x8*>(&Wb[((size_t)ks*64 + lane)*8]);
        acc = __builtin_amdgcn_mfma_f32_16x16x32_bf16(af[ks], bf, acc, 0, 0, 0);
      }
      int f = nt*16 + mrow;
      if (f < NE) {
        #pragma unroll
        for (int reg = 0; reg < 4; reg++) {
          int m = quad*4 + reg;
          if (m < 4 && relsh[1+m] == r) hS[(1+m)*TS + f] = f2bf(acc[reg]);
        }
      }
    }
    __syncthreads();
    for (int f = tid; f < NE; f += 256) {
      float sum = 0.f;
      #pragma unroll
      for (int c = 1; c <= 4; c++) sum += bf2f(hS[c*TS + f]);
      float v = bf2f(hS[0*TS + f]) * sum * 0.25f;
      root[(size_t)sb*NE + f] = v > 0.f ? v : 0.f;
    }
  }
}

// ---------------- k_feat: X (concat feature) in A-frag swizzled bf16 -------
// A-frag layout: lane holds row m=lane&15, k=(lane>>4)*8+i.
// Xsw[((kt*16 + mt)*64 + lane)*8 + i] = bf16(x[mt*16+(lane&15)][kt*32+(lane>>4)*8+i])
constexpr int FEAT_ITEMS  = KT0*16*64;          // 58,368
constexpr int FEAT_BLOCKS = FEAT_ITEMS/256;     // 228 exactly

__global__ __launch_bounds__(256)
void k_feat(const float* __restrict__ rep, const float* __restrict__ root,
            ushort* __restrict__ Xsw) {
  int t = blockIdx.x*256 + threadIdx.x;
  int lane = t & 63, g = t >> 6;
  int mt = g % 16, kt = g / 16;
  int b  = mt*16 + (lane & 15);
  int kb = kt*32 + (lane >> 4)*8;
  const float* rp = rep  + (size_t)b*NE;
  const float* rh = rep  + (size_t)(NB+b)*NE;
  const float* tp = root + (size_t)b*NE;
  const float* th = root + (size_t)(NB+b)*NE;
  ushort v[8];
  #pragma unroll
  for (int i = 0; i < 8; i++) {
    int k = kb + i;
    float x = 0.f;
    if (k < 6*NE) {
      int seg = k / NE, e = k - seg*NE;
      switch (seg) {
        case 0:  x = rp[e]; break;
        case 1:  x = rh[e]; break;
        case 2:  x = rp[e] - rh[e]; break;
        case 3:  x = rp[e] * rh[e]; break;
        case 4:  x = tp[e] - th[e]; break;
        default: x = tp[e] * th[e]; break;
      }
    }
    v[i] = f2bf(x);
  }
  *reinterpret_cast<int4*>(&Xsw[(size_t)t*8]) = *reinterpret_cast<const int4*>(v);
}

// ---------------- k_gemm: bf16 MFMA FC layer, bias+relu fused --------------
// Grid (4,10), 256 threads = 4 waves. Wave computes 16 rows x 64 cols via
// 4 accumulators. No LDS, no atomics. mode 0: A = Xsw (frag-swizzled);
// mode 1: A = h bf16 row-major [NB][HP] (scattered 16B frag loads, L2-hot).
__device__ __forceinline__ void fc_epi(f32x4 acc, int row, int j,
                                       const float* __restrict__ bias,
                                       ushort* __restrict__ hout) {
  float bj = (j < NH) ? bias[j] : 0.f;
  #pragma unroll
  for (int r = 0; r < 4; r++) {
    float v = acc[r] + bj;
    v = v > 0.f ? v : 0.f;
    if (j < 608) hout[(size_t)(row + r)*HP + j] = f2bf(v);
  }
}

__global__ __launch_bounds__(256)
void k_gemm(const ushort* __restrict__ A, const ushort* __restrict__ Wsw,
            const float* __restrict__ bias, ushort* __restrict__ hout,
            int nstep, int mode) {
  const int tid = threadIdx.x;
  const int wv = tid >> 6, lane = tid & 63;
  const int bx = blockIdx.x, by = blockIdx.y;
  const int b0 = bx*64, j0 = by*64;

  const ushort* ap;
  size_t astride;
  if (mode == 0) {
    ap = A + ((size_t)((size_t)bx*4 + wv)*64 + lane)*8;   // mt = bx*4+wv
    astride = (size_t)16*64*8;                             // next kt
  } else {
    ap = A + (size_t)(b0 + wv*16 + (lane & 15))*HP + (lane >> 4)*8;
    astride = 32;
  }
  const ushort* wp = Wsw + ((size_t)(by*4)*64 + lane)*8;
  constexpr size_t WSTRIDE = (size_t)NJT*64*8;   // 20480 per kt

  f32x4 acc0{0.f,0.f,0.f,0.f}, acc1{0.f,0.f,0.f,0.f};
  f32x4 acc2{0.f,0.f,0.f,0.f}, acc3{0.f,0.f,0.f,0.f};
  for (int t = 0; t < nstep; t++) {
    bf16x8 a  = *reinterpret_cast<const bf16x8*>(ap);
    bf16x8 w0 = *reinterpret_cast<const bf16x8*>(wp);
    bf16x8 w1 = *reinterpret_cast<const bf16x8*>(wp + 512);
    bf16x8 w2 = *reinterpret_cast<const bf16x8*>(wp + 1024);
    bf16x8 w3 = *reinterpret_cast<const bf16x8*>(wp + 1536);
    acc0 = __builtin_amdgcn_mfma_f32_16x16x32_bf16(a, w0, acc0, 0, 0, 0);
    acc1 = __builtin_amdgcn_mfma_f32_16x16x32_bf16(a, w1, acc1, 0, 0, 0);
    acc2 = __builtin_amdgcn_mfma_f32_16x16x32_bf16(a, w2, acc2, 0, 0, 0);
    acc3 = __builtin_amdgcn_mfma_f32_16x16x32_bf16(a, w3, acc3, 0, 0, 0);
    ap += astride;
    wp += WSTRIDE;
  }
  // C/D layout: col = lane&15, row = (lane>>4)*4 + reg
  int row = b0 + wv*16 + (lane >> 4)*4;
  int jb  = j0 + (lane & 15);
  fc_epi(acc0, row, jb +  0, bias, hout);
  fc_epi(acc1, row, jb + 16, bias, hout);
  fc_epi(acc2, row, jb + 32, bias, hout);
  fc_epi(acc3, row, jb + 48, bias, hout);
}

// ---------------- k_out: 600->3, h3 bf16 (relu already applied) ------------
__global__ __launch_bounds__(64)
void k_out(const ushort* __restrict__ h3, const float* __restrict__ Wout,
           const float* __restrict__ bout, float* __restrict__ out) {
  int b = blockIdx.x, tid = threadIdx.x;
  float a0 = 0.f, a1 = 0.f, a2 = 0.f;
  for (int k = tid; k < NH; k += 64) {
    float xv = bf2f(h3[(size_t)b*HP + k]);
    a0 += xv * Wout[k];
    a1 += xv * Wout[NH + k];
    a2 += xv * Wout[2*NH + k];
  }
  #pragma unroll
  for (int off = 32; off > 0; off >>= 1) {
    a0 += __shfl_down(a0, off, 64);
    a1 += __shfl_down(a1, off, 64);
    a2 += __shfl_down(a2, off, 64);
  }
  if (tid == 0) {
    out[b*3 + 0] = a0 + bout[0];
    out[b*3 + 1] = a1 + bout[1];
    out[b*3 + 2] = a2 + bout[2];
  }
}

// ---------------- launch ----------------
extern "C" void kernel_launch(void* const* d_in, const int* in_sizes, int n_in,
                              void* d_out, int out_size, void* d_ws, size_t ws_size,
                              hipStream_t stream) {
  const int*   px    = (const int*)d_in[0];
  const int*   hx    = (const int*)d_in[1];
  const int*   pwi   = (const int*)d_in[2];
  const int*   prel  = (const int*)d_in[3];
  const int*   hwi   = (const int*)d_in[4];
  const int*   hrel  = (const int*)d_in[5];
  // d_in[6]=parent, d_in[7]=level: fixed 4-ary tree, hardcoded
  const float* Etab  = (const float*)d_in[8];
  const float* Wenc  = (const float*)d_in[9];
  const float* W0w   = (const float*)d_in[10];
  const float* W0b   = (const float*)d_in[11];
  const float* W1w   = (const float*)d_in[12];
  const float* W1b   = (const float*)d_in[13];
  const float* W2w   = (const float*)d_in[14];
  const float* W2b   = (const float*)d_in[15];
  const float* Woutw = (const float*)d_in[16];
  const float* Woutb = (const float*)d_in[17];

  float* ws   = (float*)d_ws;
  float*  rep  = ws + OFF_REP;
  float*  root = ws + OFF_ROOT;
  ushort* Wbf  = (ushort*)(ws + OFF_WBF);
  ushort* W0S  = (ushort*)(ws + OFF_W0S);
  ushort* W1S  = (ushort*)(ws + OFF_W1S);
  ushort* W2S  = (ushort*)(ws + OFF_W2S);
  ushort* Xsw  = (ushort*)(ws + OFF_XSW);
  ushort* h1   = (ushort*)(ws + OFF_H1);
  ushort* h2   = (ushort*)(ws + OFF_H2);
  ushort* h3   = (ushort*)(ws + OFF_H3);
  float* outp = (float*)d_out;

  dim3 blk(256);
  k_setup<<<dim3(SETUP_BLOCKS), blk, 0, stream>>>(
      Wenc, W0w, W1w, W2w, Wbf, W0S, W1S, W2S);
  k_tree<<<dim3(2*NB), blk, 0, stream>>>(
      px, hx, pwi, prel, hwi, hrel, Etab, Wbf, rep, root);
  k_feat<<<dim3(FEAT_BLOCKS), blk, 0, stream>>>(rep, root, Xsw);
  k_gemm<<<dim3(4,10), blk, 0, stream>>>(Xsw, W0S, W0b, h1, KT0, 0);
  k_gemm<<<dim3(4,10), blk, 0, stream>>>(h1,  W1S, W1b, h2, KT1, 1);
  k_gemm<<<dim3(4,10), blk, 0, stream>>>(h2,  W2S, W2b, h3, KT1, 1);
  k_out<<<dim3(NB), dim3(64), 0, stream>>>(h3, Woutw, Woutb, outp);
}